// Round 3
// baseline (1427.097 us; speedup 1.0000x reference)
//
#include <hip/hip_runtime.h>

#define NP   524288
#define RES  512
#define CH   16
#define DIMS 48
#define HID  256
#define PPT  2
#define TPB  256
#define PLANE_ELEMS (CH * RES * RES)   // 4,194,304

__device__ __forceinline__ float lrelu(float x) { return x >= 0.0f ? x : 0.01f * x; }

// ---------------- precompute kernels ----------------

// (16,512,512) -> (512,512,16), one plane.
__global__ __launch_bounds__(TPB) void transpose_plane(const float* __restrict__ in,
                                                       float* __restrict__ outp) {
    __shared__ float s[CH][TPB];
    const int pos = blockIdx.x * TPB;          // 256 consecutive (y*512+x) positions
    const int tid = threadIdx.x;
#pragma unroll
    for (int c = 0; c < CH; ++c)
        s[c][tid] = in[c * (RES * RES) + pos + tid];   // coalesced 1KB per c
    __syncthreads();
    float4* o = (float4*)(outp + (size_t)(pos + tid) * CH);
#pragma unroll
    for (int v = 0; v < 4; ++v) {
        float4 r;
        r.x = s[v * 4 + 0][tid]; r.y = s[v * 4 + 1][tid];
        r.z = s[v * 4 + 2][tid]; r.w = s[v * 4 + 3][tid];
        o[v] = r;                                      // coalesced 64B per thread
    }
}

// Collapse time-plane x-dimension at fixed t: tcol[pl][y][c] =
// wx0*plane[c][y][x0c] + wx1*plane[c][y][x1c].  6*512*16 outputs.
__global__ __launch_bounds__(TPB) void build_tcol(const float* __restrict__ tsp,
                                                  const float* __restrict__ time_emb,
                                                  float* __restrict__ tcol) {
    const int idx = blockIdx.x * TPB + threadIdx.x;
    if (idx >= 6 * RES * CH) return;
    const int c  = idx & 15;
    const int y  = (idx >> 4) & (RES - 1);
    const int pl = idx >> 13;
    const float t = *time_emb;
    const float ix = (t + 1.0f) * 0.5f * (float)(RES - 1);
    const float fx0 = floorf(ix);
    const float wx1 = ix - fx0, wx0 = fx0 + 1.0f - ix;
    const int x0 = min(max((int)fx0, 0), RES - 1);
    const int x1 = min(max((int)fx0 + 1, 0), RES - 1);
    const float* base = tsp + ((size_t)pl * CH + c) * (RES * RES) + y * RES;
    tcol[idx] = wx0 * base[x0] + wx1 * base[x1];
}

// w2t[p][j][c] = cw2[p][c][j]   (3,256,16)
__global__ __launch_bounds__(TPB) void build_w2t(const float* __restrict__ cw2,
                                                 float* __restrict__ w2t) {
    const int idx = blockIdx.x * TPB + threadIdx.x;
    if (idx >= 3 * HID * CH) return;
    const int c = idx & 15;
    const int j = (idx >> 4) & (HID - 1);
    const int p = idx >> 12;
    w2t[idx] = cw2[p * CH * HID + c * HID + j];
}

// ---------------- fused per-plane kernel ----------------

__global__ __launch_bounds__(TPB) void tensor4d_fused(
    const float* __restrict__ xyz,     // (NP, 3)
    const float* __restrict__ spt,     // (512, 512, 16) transposed space plane (ws)
    const float* __restrict__ tcol,    // (6, 512, 16) collapsed time columns (ws)
    const float* __restrict__ cw1,     // (3, 256, 48)
    const float* __restrict__ cb1,     // (3, 256)
    const float* __restrict__ w2t,     // (3, 256, 16) transposed layer-2 (ws)
    const float* __restrict__ cb2,     // (3, 16)
    float* __restrict__ out,           // (NP, 48)
    int p)
{
    __shared__ float s_w1[HID * DIMS];      // 48 KB

    // Stage layer-1 weights for this plane into LDS.
    {
        const float4* src = (const float4*)(cw1 + p * HID * DIMS);
        float4* dst = (float4*)s_w1;
        for (int idx = threadIdx.x; idx < HID * DIMS / 4; idx += TPB)
            dst[idx] = src[idx];
    }
    __syncthreads();

    const int m0 = (p == 0) ? 1 : 0;        // matMode
    const int m1 = (p == 2) ? 1 : 2;
    const float* t0col = tcol + (2 * p) * (RES * CH);
    const float* t1col = tcol + (2 * p + 1) * (RES * CH);

    const int base = blockIdx.x * (TPB * PPT) + threadIdx.x;

    float f[PPT][DIMS];
#pragma unroll
    for (int q = 0; q < PPT; ++q) {
        const int i = base + q * TPB;
        const float c0 = xyz[i * 3 + m0];
        const float c1 = xyz[i * 3 + m1];

        // ---- space plane: bilinear at (x=c0, y=c1), channels-last ----
        {
            const float ix = (c0 + 1.0f) * 0.5f * (float)(RES - 1);
            const float iy = (c1 + 1.0f) * 0.5f * (float)(RES - 1);
            const float fx0 = floorf(ix), fy0 = floorf(iy);
            const float wx1 = ix - fx0, wx0 = fx0 + 1.0f - ix;
            const float wy1 = iy - fy0, wy0 = fy0 + 1.0f - iy;
            const int x0 = min(max((int)fx0, 0), RES - 1);
            const int x1 = min(max((int)fx0 + 1, 0), RES - 1);
            const int y0 = min(max((int)fy0, 0), RES - 1);
            const int y1 = min(max((int)fy0 + 1, 0), RES - 1);
            const float w00 = wx0 * wy0, w01 = wx1 * wy0;
            const float w10 = wx0 * wy1, w11 = wx1 * wy1;
            const float4* p00 = (const float4*)(spt + (size_t)(y0 * RES + x0) * CH);
            const float4* p01 = (const float4*)(spt + (size_t)(y0 * RES + x1) * CH);
            const float4* p10 = (const float4*)(spt + (size_t)(y1 * RES + x0) * CH);
            const float4* p11 = (const float4*)(spt + (size_t)(y1 * RES + x1) * CH);
#pragma unroll
            for (int v = 0; v < 4; ++v) {
                const float4 a = p00[v], b = p01[v], c = p10[v], d = p11[v];
                f[q][v * 4 + 0] = a.x * w00 + b.x * w01 + c.x * w10 + d.x * w11;
                f[q][v * 4 + 1] = a.y * w00 + b.y * w01 + c.y * w10 + d.y * w11;
                f[q][v * 4 + 2] = a.z * w00 + b.z * w01 + c.z * w10 + d.z * w11;
                f[q][v * 4 + 3] = a.w * w00 + b.w * w01 + c.w * w10 + d.w * w11;
            }
        }

        // ---- time planes: y-lerp of precollapsed columns ----
#pragma unroll
        for (int s = 0; s < 2; ++s) {
            const float cc = (s == 0) ? c0 : c1;
            const float* tc = (s == 0) ? t0col : t1col;
            const float iy = (cc + 1.0f) * 0.5f * (float)(RES - 1);
            const float fy0 = floorf(iy);
            const float wy1 = iy - fy0, wy0 = fy0 + 1.0f - iy;
            const int y0 = min(max((int)fy0, 0), RES - 1);
            const int y1 = min(max((int)fy0 + 1, 0), RES - 1);
            const float4* q0 = (const float4*)(tc + y0 * CH);
            const float4* q1 = (const float4*)(tc + y1 * CH);
            float* fo = &f[q][CH + s * CH];
#pragma unroll
            for (int v = 0; v < 4; ++v) {
                const float4 a = q0[v], b = q1[v];
                fo[v * 4 + 0] = a.x * wy0 + b.x * wy1;
                fo[v * 4 + 1] = a.y * wy0 + b.y * wy1;
                fo[v * 4 + 2] = a.z * wy0 + b.z * wy1;
                fo[v * 4 + 3] = a.w * wy0 + b.w * wy1;
            }
        }
    }

    // ---- MLP: 48 -> 256 (lrelu) -> 16 (lrelu), fp32 ----
    float acc[PPT][CH];
#pragma unroll
    for (int q = 0; q < PPT; ++q)
#pragma unroll
        for (int c = 0; c < CH; ++c) acc[q][c] = 0.0f;

    const float* b1p  = cb1 + p * HID;
    const float* w2tp = w2t + p * HID * CH;

    for (int j = 0; j < HID; ++j) {
        const float b = b1p[j];                        // wave-uniform
        float h[PPT];
#pragma unroll
        for (int q = 0; q < PPT; ++q) h[q] = b;

        const float4* wrow = (const float4*)(&s_w1[j * DIMS]);  // uniform -> LDS broadcast
#pragma unroll
        for (int kk = 0; kk < DIMS / 4; ++kk) {
            const float4 w = wrow[kk];
#pragma unroll
            for (int q = 0; q < PPT; ++q) {
                h[q] = fmaf(w.x, f[q][kk * 4 + 0], h[q]);
                h[q] = fmaf(w.y, f[q][kk * 4 + 1], h[q]);
                h[q] = fmaf(w.z, f[q][kk * 4 + 2], h[q]);
                h[q] = fmaf(w.w, f[q][kk * 4 + 3], h[q]);
            }
        }
#pragma unroll
        for (int q = 0; q < PPT; ++q) h[q] = lrelu(h[q]);

        const float4* w2row = (const float4*)(w2tp + j * CH);   // uniform 64B row
#pragma unroll
        for (int v = 0; v < 4; ++v) {
            const float4 wv = w2row[v];
#pragma unroll
            for (int q = 0; q < PPT; ++q) {
                acc[q][v * 4 + 0] = fmaf(wv.x, h[q], acc[q][v * 4 + 0]);
                acc[q][v * 4 + 1] = fmaf(wv.y, h[q], acc[q][v * 4 + 1]);
                acc[q][v * 4 + 2] = fmaf(wv.z, h[q], acc[q][v * 4 + 2]);
                acc[q][v * 4 + 3] = fmaf(wv.w, h[q], acc[q][v * 4 + 3]);
            }
        }
    }

    // ---- epilogue: bias + lrelu, float4 stores ----
#pragma unroll
    for (int q = 0; q < PPT; ++q) {
        const int i = base + q * TPB;
        float4* o = (float4*)(out + (size_t)i * DIMS + p * CH);
#pragma unroll
        for (int v = 0; v < 4; ++v) {
            float4 r;
            r.x = lrelu(acc[q][v * 4 + 0] + cb2[p * CH + v * 4 + 0]);
            r.y = lrelu(acc[q][v * 4 + 1] + cb2[p * CH + v * 4 + 1]);
            r.z = lrelu(acc[q][v * 4 + 2] + cb2[p * CH + v * 4 + 2]);
            r.w = lrelu(acc[q][v * 4 + 3] + cb2[p * CH + v * 4 + 3]);
            o[v] = r;
        }
    }
}

// ---------------- launch ----------------

extern "C" void kernel_launch(void* const* d_in, const int* in_sizes, int n_in,
                              void* d_out, int out_size, void* d_ws, size_t ws_size,
                              hipStream_t stream) {
    const float* xyz          = (const float*)d_in[0];
    const float* time_emb     = (const float*)d_in[1];
    const float* space_planes = (const float*)d_in[2];
    const float* tsp          = (const float*)d_in[3];
    const float* cw1          = (const float*)d_in[4];
    const float* cb1          = (const float*)d_in[5];
    const float* cw2          = (const float*)d_in[6];
    const float* cb2          = (const float*)d_in[7];
    float* out = (float*)d_out;

    // workspace layout (floats): [spt: 4,194,304][tcol: 49,152][w2t: 12,288]
    float* spt  = (float*)d_ws;
    float* tcol = spt + (size_t)RES * RES * CH;
    float* w2t  = tcol + 6 * RES * CH;

    build_tcol<<<dim3((6 * RES * CH + TPB - 1) / TPB), dim3(TPB), 0, stream>>>(tsp, time_emb, tcol);
    build_w2t<<<dim3((3 * HID * CH + TPB - 1) / TPB), dim3(TPB), 0, stream>>>(cw2, w2t);

    for (int p = 0; p < 3; ++p) {
        transpose_plane<<<dim3(RES * RES / TPB), dim3(TPB), 0, stream>>>(
            space_planes + (size_t)p * PLANE_ELEMS, spt);
        tensor4d_fused<<<dim3(NP / (TPB * PPT)), dim3(TPB), 0, stream>>>(
            xyz, spt, tcol, cw1, cb1, w2t, cb2, out, p);
    }
}